// Round 10
// baseline (177.317 us; speedup 1.0000x reference)
//
#include <hip/hip_runtime.h>

#define TPB 256

// Gaussian kernel, sigma=1.1, ksize=5 (precomputed, normalized)
#define K0 0.0707663f
#define K1 0.2444606f
#define K2 0.3695462f

// energy blocks: scale0 LDS-tiled: 2b*160x*5ty*5tz = 8000 ; scales 1,2 per-f4
#define EB0 8000
#define EB1 1000
#define EB2 125
// gradmag y4-unit block counts
#define GB0 2000
#define GB1 250
#define GB2 32      // guard idx<8000
// blur y4-units per scale
#define BB0 2000
#define BB1 250
#define BB2 32      // guard idx<8000
// resize: total outputs 4,608,000 ; 2 per thread -> 9000 blocks
#define RHALF 2304000L
#define RBLK 9000

typedef float f4 __attribute__((ext_vector_type(4)));

__device__ __forceinline__ f4 ld4(const float* __restrict__ p) { return *(const f4*)p; }

// reflect index (no edge repeat): j<0 -> -j, j>=n -> 2n-2-j
__device__ __forceinline__ int rref(int i, int n) {
    return i < 0 ? -i : (i >= n ? 2 * n - 2 - i : i);
}

// -------- trilinear resize (device helper), align_corners --------
template <int NIN, int M>
__device__ __forceinline__ void resize_one(const float* __restrict__ in,
                                           float* __restrict__ out, long idx) {
    constexpr float ratio = (float)((NIN - 1.0) / (M - 1.0));
    int z = (int)(idx % M); long r = idx / M;
    int y = (int)(r % M);   r /= M;
    int x = (int)(r % M);   int bc = (int)(r / M);

    float cx = (float)x * ratio, cy = (float)y * ratio, cz = (float)z * ratio;
    int x0 = min((int)cx, NIN - 1), y0 = min((int)cy, NIN - 1), z0 = min((int)cz, NIN - 1);
    float wx = cx - (float)x0, wy = cy - (float)y0, wz = cz - (float)z0;
    int x1 = min(x0 + 1, NIN - 1), y1 = min(y0 + 1, NIN - 1), z1 = min(z0 + 1, NIN - 1);

    const float* p = in + (long)bc * NIN * NIN * NIN;
    constexpr long sx = (long)NIN * NIN;
#define AT(xi, yi, zi) p[(long)(xi) * sx + (long)(yi) * NIN + (zi)]
    float c00 = AT(x0, y0, z0) * (1.f - wz) + AT(x0, y0, z1) * wz;
    float c01 = AT(x0, y1, z0) * (1.f - wz) + AT(x0, y1, z1) * wz;
    float c10 = AT(x1, y0, z0) * (1.f - wz) + AT(x1, y0, z1) * wz;
    float c11 = AT(x1, y1, z0) * (1.f - wz) + AT(x1, y1, z1) * wz;
#undef AT
    float c0 = c00 * (1.f - wy) + c01 * wy;
    float c1 = c10 * (1.f - wy) + c11 * wy;
    out[idx] = c0 * (1.f - wx) + c1 * wx;
}

__device__ __forceinline__ void resize_dispatch(const float* __restrict__ D,
                                                const float* __restrict__ I,
                                                float* __restrict__ ds1, float* __restrict__ ds2,
                                                float* __restrict__ is1, float* __restrict__ is2,
                                                long idx) {
    if (idx < 3072000L) { resize_one<160, 80>(D, ds1, idx); return; }
    idx -= 3072000L;
    if (idx < 384000L) { resize_one<160, 40>(D, ds2, idx); return; }
    idx -= 384000L;
    if (idx < 1024000L) { resize_one<160, 80>(I, is1, idx); return; }
    idx -= 1024000L;
    resize_one<160, 40>(I, is2, idx);
}

__global__ __launch_bounds__(TPB)
void resize_all_kernel(const float* __restrict__ D, const float* __restrict__ I,
                       float* __restrict__ ds1, float* __restrict__ ds2,
                       float* __restrict__ is1, float* __restrict__ is2) {
    long idx = (long)blockIdx.x * TPB + threadIdx.x;
    resize_dispatch(D, I, ds1, ds2, is1, is2, idx);
    resize_dispatch(D, I, ds1, ds2, is1, is2, idx + RHALF);
}

// -------- gradient magnitude, 4 y-rows per thread (sliding 3-row window) --------
template <int N>
__device__ __forceinline__ void gradmag_y4(const float* __restrict__ img,
                                           float* __restrict__ g, long idx) {
    constexpr int NZ4 = N / 4, NY4 = N / 4;
    constexpr long n2 = (long)N * N, n3 = n2 * N;
    int z4 = (int)(idx % NZ4); long r = idx / NZ4;
    int y4 = (int)(r % NY4); r /= NY4;
    int x = (int)(r % N); int b = (int)(r / N);
    int y0 = y4 * 4, z = z4 * 4;

    int xm = max(x - 1, 0), xp = min(x + 1, N - 1);
    float hx = (x == 0 || x == N - 1) ? 1.f : 0.5f;

    const float* base = img + (long)b * n3;
    const float* colx = base + (long)x * n2;
    float* gb = g + (long)b * n3 + (long)x * n2 + z;

    f4 Im = ld4(colx + (long)max(y0 - 1, 0) * N + z);
    f4 Ic = ld4(colx + (long)y0 * N + z);

#pragma unroll
    for (int jy = 0; jy < 4; ++jy) {
        int y = y0 + jy;
        int yp = min(y + 1, N - 1);
        float hy = (y == 0 || y == N - 1) ? 1.f : 0.5f;
        f4 Ip = ld4(colx + (long)yp * N + z);
        const float* rowy = colx + (long)y * N;
        f4 prev = (z > 0) ? ld4(rowy + z - 4) : Ic;
        f4 next = (z + 4 < N) ? ld4(rowy + z + 4) : Ic;
        f4 rxp = ld4(base + (long)xp * n2 + (long)y * N + z);
        f4 rxm = ld4(base + (long)xm * n2 + (long)y * N + z);

        f4 outv;
#pragma unroll
        for (int j = 0; j < 4; ++j) {
            float c = Ic[j];
            float zmv = (j == 0) ? prev[3] : Ic[(j == 0) ? 0 : j - 1];
            float zpv = (j == 3) ? next[0] : Ic[(j == 3) ? 3 : j + 1];
            int gz = z + j;
            float dz = (gz == 0) ? (zpv - c) : ((gz == N - 1) ? (c - zmv) : 0.5f * (zpv - zmv));
            float dx = hx * (rxp[j] - rxm[j]);
            float dy = hy * (Ip[j] - Im[j]);
            outv[j] = sqrtf(dx * dx + dy * dy + dz * dz);
        }
        *(f4*)(gb + (long)y * N) = outv;

        Im = Ic; Ic = Ip;
    }
}

__global__ __launch_bounds__(TPB)
void gradmag_all(const float* __restrict__ I0, const float* __restrict__ is1,
                 const float* __restrict__ is2, float* __restrict__ g0,
                 float* __restrict__ g1, float* __restrict__ g2) {
    int blk = blockIdx.x;
    if (blk < GB0)            gradmag_y4<160>(I0,  g0, (long)blk * TPB + threadIdx.x);
    else if (blk < GB0 + GB1) gradmag_y4<80> (is1, g1, (long)(blk - GB0) * TPB + threadIdx.x);
    else {
        long idx = (long)(blk - GB0 - GB1) * TPB + threadIdx.x;
        if (idx < 8000) gradmag_y4<40>(is2, g2, idx);
    }
}

// -------- fused blur x+y, 4 outputs per thread along y (column-sum reuse) --------
template <int N>
__device__ __forceinline__ void blur_one(const float* __restrict__ in,
                                         float* __restrict__ out, long idx) {
    constexpr int NZ4 = N / 4, NY4 = N / 4;
    constexpr long n2 = (long)N * N, n3 = n2 * N;
    int z4 = (int)(idx % NZ4); long r = idx / NZ4;
    int y4 = (int)(r % NY4); r /= NY4;
    int x = (int)(r % N); int b = (int)(r / N);
    int y0 = y4 * 4, z = z4 * 4;

    const float K[5] = {K0, K1, K2, K1, K0};
    const float* base = in + (long)b * n3 + z;

    f4 cs[8];
#pragma unroll
    for (int jj = 0; jj < 8; ++jj) cs[jj] = (f4){0.f, 0.f, 0.f, 0.f};

#pragma unroll
    for (int i = 0; i < 5; ++i) {
        int qx = rref(x + i - 2, N);
        const float* px = base + (long)qx * n2;
#pragma unroll
        for (int jj = 0; jj < 8; ++jj) {
            int qy = rref(y0 - 2 + jj, N);
            cs[jj] += K[i] * ld4(px + (long)qy * N);
        }
    }
    float* ob = out + (long)b * n3 + (long)x * n2 + z;
#pragma unroll
    for (int k = 0; k < 4; ++k) {
        f4 o = K0 * cs[k] + K1 * cs[k + 1] + K2 * cs[k + 2] + K1 * cs[k + 3] + K0 * cs[k + 4];
        *(f4*)(ob + (long)(y0 + k) * N) = o;
    }
}

__global__ __launch_bounds__(TPB)
void blur_all(const float* __restrict__ g0, const float* __restrict__ g1,
              const float* __restrict__ g2, float* __restrict__ t0,
              float* __restrict__ t1, float* __restrict__ t2) {
    int blk = blockIdx.x;
    if (blk < BB0)            blur_one<160>(g0, t0, (long)blk * TPB + threadIdx.x);
    else if (blk < BB0 + BB1) blur_one<80> (g1, t1, (long)(blk - BB0) * TPB + threadIdx.x);
    else {
        long idx = (long)(blk - BB0 - BB1) * TPB + threadIdx.x;
        if (idx < 8000) blur_one<40>(g2, t2, idx);
    }
}

// -------- Lame strain energy + in-register blur-z of igxy (global path, per f4) ----
template <int N>
__device__ __forceinline__ float energy_one(const float* __restrict__ def,
                                            const float* __restrict__ igxy, long idx) {
    constexpr int NZ4 = N / 4;
    constexpr long n2 = (long)N * N, n3 = n2 * N;
    int z4 = (int)(idx % NZ4); long r = idx / NZ4;
    int y = (int)(r % N); r /= N;
    int x = (int)(r % N); int b = (int)(r / N);
    int z = z4 * 4;

    int xm = max(x - 1, 0), xp = min(x + 1, N - 1);
    int ym = max(y - 1, 0), yp = min(y + 1, N - 1);
    float hx = (x == 0 || x == N - 1) ? 1.f : 0.5f;
    float hy = (y == 0 || y == N - 1) ? 1.f : 0.5f;

    const float* base = def + (long)b * 3 * n3;
    long sp = (long)x * n2 + (long)y * N + z;

    f4 CC[3], CP[3], CN[3], RXP[3], RXM[3], RYP[3], RYM[3];
#pragma unroll
    for (int c = 0; c < 3; ++c) {
        const float* rc = base + (long)c * n3 + sp;
        CC[c] = ld4(rc);
        CP[c] = (z > 0) ? ld4(rc - 4) : CC[c];
        CN[c] = (z + 4 < N) ? ld4(rc + 4) : CC[c];
        RXP[c] = ld4(base + (long)c * n3 + (long)xp * n2 + (long)y * N + z);
        RXM[c] = ld4(base + (long)c * n3 + (long)xm * n2 + (long)y * N + z);
        RYP[c] = ld4(base + (long)c * n3 + (long)x * n2 + (long)yp * N + z);
        RYM[c] = ld4(base + (long)c * n3 + (long)x * n2 + (long)ym * N + z);
    }

    const float* growc = igxy + (long)b * n3 + (long)x * n2 + (long)y * N;
    f4 gcur = ld4(growc + z);
    f4 gprev, gnext;
    if (z >= 4) gprev = ld4(growc + z - 4);
    else { gprev[0] = growc[4]; gprev[1] = growc[3]; gprev[2] = growc[2]; gprev[3] = growc[1]; }
    if (z + 8 <= N) gnext = ld4(growc + z + 4);
    else { gnext[0] = growc[N - 2]; gnext[1] = growc[N - 3]; gnext[2] = growc[N - 4]; gnext[3] = growc[N - 5]; }
    float gw[12];
#pragma unroll
    for (int i = 0; i < 4; ++i) { gw[i] = gprev[i]; gw[4 + i] = gcur[i]; gw[8 + i] = gnext[i]; }

    float lsum = 0.f;
#pragma unroll
    for (int j = 0; j < 4; ++j) {
        int gz = z + j;
        float dX[3], dY[3], dZ[3];
#pragma unroll
        for (int c = 0; c < 3; ++c) {
            float cc = CC[c][j];
            float zmv = (j == 0) ? CP[c][3] : CC[c][(j == 0) ? 0 : j - 1];
            float zpv = (j == 3) ? CN[c][0] : CC[c][(j == 3) ? 3 : j + 1];
            dZ[c] = (gz == 0) ? (zpv - cc)
                              : ((gz == N - 1) ? (cc - zmv) : 0.5f * (zpv - zmv));
            dX[c] = hx * (RXP[c][j] - RXM[c][j]);
            dY[c] = hy * (RYP[c][j] - RYM[c][j]);
        }
        float igv = K0 * gw[2 + j] + K1 * gw[3 + j] + K2 * gw[4 + j]
                  + K1 * gw[5 + j] + K0 * gw[6 + j];
        float lam = fminf(fmaxf(1.0f + 2.0f * igv, 0.1f), 10.0f);
        float mu  = fminf(fmaxf(0.5f + 1.0f * igv, 0.1f), 10.0f);
        float wt  = 1.0f + 5.0f * igv;

        float Exx = dX[0], Eyy = dY[1], Ezz = dZ[2];
        float Exy = 0.5f * (dY[0] + dX[1]);
        float Exz = 0.5f * (dZ[0] + dX[2]);
        float Eyz = 0.5f * (dZ[1] + dY[2]);
        float tr = Exx + Eyy + Ezz;
        float e = 0.5f * lam * tr * tr +
                  mu * (Exx * Exx + Eyy * Eyy + Ezz * Ezz +
                        2.0f * (Exy * Exy + Exz * Exz + Eyz * Eyz));
        lsum += wt * e;
    }
    return lsum;
}

// -------- energy: scale0 LDS-tiled (32y x 32z per block), scales 1-2 global --------
__global__ __launch_bounds__(TPB)
void energy_all(const float* __restrict__ D, const float* __restrict__ ds1,
                const float* __restrict__ ds2, const float* __restrict__ t0,
                const float* __restrict__ t1, const float* __restrict__ t2,
                float* __restrict__ partial) {
    __shared__ float dl[3][34][40];  // 3ch x (32y+2 halo) x (32z+8 halo, f4-aligned)
    __shared__ float sm[TPB];
    int blk = blockIdx.x;
    float lsum = 0.f;

    if (blk < EB0) {
        constexpr int N = 160;
        constexpr long n2 = (long)N * N, n3 = n2 * N;
        int tz = blk % 5; int r = blk / 5;
        int ty = r % 5; r /= 5;
        int x = r % N; int b = r / N;
        int Y0 = ty * 32, Z0 = tz * 32;

        // stage 3-channel def tile: y in [Y0-1, Y0+32], z f4-slots [Z0-4, Z0+36)
        const float* db = D + (long)b * 3 * n3 + (long)x * n2;
        for (int i = threadIdx.x; i < 1020; i += TPB) {
            int ch = i / 340; int rem = i - ch * 340;
            int yy = rem / 10; int s = rem - yy * 10;
            int gy = min(max(Y0 - 1 + yy, 0), N - 1);
            int gz = min(max(Z0 - 4 + 4 * s, 0), N - 4);
            *(f4*)&dl[ch][yy][4 * s] = ld4(db + (long)ch * n3 + (long)gy * N + gz);
        }
        __syncthreads();

        int ly = threadIdx.x >> 3, lz4 = threadIdx.x & 7;
        int y = Y0 + ly, z = Z0 + lz4 * 4;
        int xm = max(x - 1, 0), xp = min(x + 1, N - 1);
        float hx = (x == 0 || x == N - 1) ? 1.f : 0.5f;
        float hy = (y == 0 || y == N - 1) ? 1.f : 0.5f;
        const float* base = D + (long)b * 3 * n3;

        f4 CC[3], CP[3], CN[3], RYP[3], RYM[3], RXP[3], RXM[3];
#pragma unroll
        for (int c = 0; c < 3; ++c) {
            CC[c]  = *(const f4*)&dl[c][ly + 1][4 + lz4 * 4];
            CP[c]  = *(const f4*)&dl[c][ly + 1][lz4 * 4];       // z-4 (clamped-junk unused at gz==0)
            CN[c]  = *(const f4*)&dl[c][ly + 1][8 + lz4 * 4];   // z+4 (clamped-junk unused at gz==N-1)
            RYM[c] = *(const f4*)&dl[c][ly][4 + lz4 * 4];
            RYP[c] = *(const f4*)&dl[c][ly + 2][4 + lz4 * 4];
            RXP[c] = ld4(base + (long)c * n3 + (long)xp * n2 + (long)y * N + z);
            RXM[c] = ld4(base + (long)c * n3 + (long)xm * n2 + (long)y * N + z);
        }

        const float* growc = t0 + (long)b * n3 + (long)x * n2 + (long)y * N;
        f4 gcur = ld4(growc + z);
        f4 gprev, gnext;
        if (z >= 4) gprev = ld4(growc + z - 4);
        else { gprev[0] = growc[4]; gprev[1] = growc[3]; gprev[2] = growc[2]; gprev[3] = growc[1]; }
        if (z + 8 <= N) gnext = ld4(growc + z + 4);
        else { gnext[0] = growc[N - 2]; gnext[1] = growc[N - 3]; gnext[2] = growc[N - 4]; gnext[3] = growc[N - 5]; }
        float gw[12];
#pragma unroll
        for (int i = 0; i < 4; ++i) { gw[i] = gprev[i]; gw[4 + i] = gcur[i]; gw[8 + i] = gnext[i]; }

#pragma unroll
        for (int j = 0; j < 4; ++j) {
            int gz = z + j;
            float dX[3], dY[3], dZ[3];
#pragma unroll
            for (int c = 0; c < 3; ++c) {
                float cc = CC[c][j];
                float zmv = (j == 0) ? CP[c][3] : CC[c][(j == 0) ? 0 : j - 1];
                float zpv = (j == 3) ? CN[c][0] : CC[c][(j == 3) ? 3 : j + 1];
                dZ[c] = (gz == 0) ? (zpv - cc)
                                  : ((gz == N - 1) ? (cc - zmv) : 0.5f * (zpv - zmv));
                dX[c] = hx * (RXP[c][j] - RXM[c][j]);
                dY[c] = hy * (RYP[c][j] - RYM[c][j]);
            }
            float igv = K0 * gw[2 + j] + K1 * gw[3 + j] + K2 * gw[4 + j]
                      + K1 * gw[5 + j] + K0 * gw[6 + j];
            float lam = fminf(fmaxf(1.0f + 2.0f * igv, 0.1f), 10.0f);
            float mu  = fminf(fmaxf(0.5f + 1.0f * igv, 0.1f), 10.0f);
            float wt  = 1.0f + 5.0f * igv;

            float Exx = dX[0], Eyy = dY[1], Ezz = dZ[2];
            float Exy = 0.5f * (dY[0] + dX[1]);
            float Exz = 0.5f * (dZ[0] + dX[2]);
            float Eyz = 0.5f * (dZ[1] + dY[2]);
            float tr = Exx + Eyy + Ezz;
            float e = 0.5f * lam * tr * tr +
                      mu * (Exx * Exx + Eyy * Eyy + Ezz * Ezz +
                            2.0f * (Exy * Exy + Exz * Exz + Eyz * Eyz));
            lsum += wt * e;
        }
    } else if (blk < EB0 + EB1) {
        lsum = energy_one<80>(ds1, t1, (long)(blk - EB0) * TPB + threadIdx.x);
    } else {
        lsum = energy_one<40>(ds2, t2, (long)(blk - EB0 - EB1) * TPB + threadIdx.x);
    }

    sm[threadIdx.x] = lsum;
    __syncthreads();
    for (int s = TPB / 2; s > 0; s >>= 1) {
        if (threadIdx.x < s) sm[threadIdx.x] += sm[threadIdx.x + s];
        __syncthreads();
    }
    if (threadIdx.x == 0) partial[blk] = sm[0];
}

// -------- combine scale partials + Jacobian penalty -> out[0] --------
__global__ __launch_bounds__(TPB)
void finalize_kernel(const float* __restrict__ partial,
                     const float* __restrict__ def, float* __restrict__ out) {
    __shared__ float sm[TPB];
    const float wts[3] = {1.0f, 0.5f, 0.25f};
    const float invcnt[3] = {1.0f / (2.0f * 160 * 160 * 160),
                             1.0f / (2.0f * 80 * 80 * 80),
                             1.0f / (2.0f * 40 * 40 * 40)};
    const int offs[3] = {0, EB0, EB0 + EB1};
    const int cnts[3] = {EB0, EB1, EB2};
    float acc = 0.f;
    for (int s = 0; s < 3; ++s) {
        float local = 0.f;
        for (int i = threadIdx.x; i < cnts[s]; i += TPB) local += partial[offs[s] + i];
        acc += wts[s] * invcnt[s] * local;
    }
    sm[threadIdx.x] = acc;
    __syncthreads();
    for (int s = TPB / 2; s > 0; s >>= 1) {
        if (threadIdx.x < s) sm[threadIdx.x] += sm[threadIdx.x + s];
        __syncthreads();
    }
    if (threadIdx.x == 0) {
        float jac = 0.f;
        const int n = 160;
        long n3 = (long)n * n * n;
        long ctr = ((long)80 * n + 80) * n + 80;
        for (int b = 0; b < 2; ++b) {
            const float* p = def + (long)b * 3 * n3;
            float J[3][3];
            for (int c = 0; c < 3; ++c) {
                const float* q = p + (long)c * n3 + ctr;
                J[c][0] = 0.5f * (q[(long)n * n] - q[-(long)n * n]);
                J[c][1] = 0.5f * (q[n] - q[-n]);
                J[c][2] = 0.5f * (q[1] - q[-1]);
            }
            float det = J[0][0] * (J[1][1] * J[2][2] - J[1][2] * J[2][1])
                      - J[0][1] * (J[1][0] * J[2][2] - J[1][2] * J[2][0])
                      + J[0][2] * (J[1][0] * J[2][1] - J[1][1] * J[2][0]);
            jac += fmaxf(-det, 0.f);
        }
        jac *= 0.5f; // mean over B=2
        out[0] = sm[0] + 0.1f * jac;
    }
}

extern "C" void kernel_launch(void* const* d_in, const int* in_sizes, int n_in,
                              void* d_out, int out_size, void* d_ws, size_t ws_size,
                              hipStream_t stream) {
    const float* D = (const float*)d_in[0];  // (2,3,160,160,160)
    const float* I = (const float*)d_in[1];  // (2,1,160,160,160)
    float* out = (float*)d_out;
    float* ws = (float*)d_ws;

    const int B = 2;
    const long S0 = (long)B * 160 * 160 * 160;
    const long S1 = (long)B * 80 * 80 * 80;
    const long S2 = (long)B * 40 * 40 * 40;

    // disjoint workspace layout
    float* partials = ws;                 // 9216 (uses [0, 9125))
    float* ds1 = partials + 9216;         // 3*S1
    float* is1 = ds1 + 3 * S1;            // S1
    float* g1  = is1 + S1;                // S1
    float* t1  = g1 + S1;                 // S1
    float* ds2 = t1 + S1;                 // 3*S2
    float* is2 = ds2 + 3 * S2;            // S2
    float* g2  = is2 + S2;                // S2
    float* t2  = g2 + S2;                 // S2
    float* g0  = t2 + S2;                 // S0
    float* t0  = g0 + S0;                 // S0

    // 1) all four resizes (2 outputs/thread)
    resize_all_kernel<<<RBLK, TPB, 0, stream>>>(D, I, ds1, ds2, is1, is2);
    // 2) gradmag, all scales (4 y-rows/thread)
    gradmag_all<<<GB0 + GB1 + GB2, TPB, 0, stream>>>(I, is1, is2, g0, g1, g2);
    // 3) blur x+y, all scales
    blur_all<<<BB0 + BB1 + BB2, TPB, 0, stream>>>(g0, g1, g2, t0, t1, t2);
    // 4) energy: scale0 LDS-tiled, scales 1-2 global
    energy_all<<<EB0 + EB1 + EB2, TPB, 0, stream>>>(D, ds1, ds2, t0, t1, t2, partials);
    // 5) finalize
    finalize_kernel<<<1, TPB, 0, stream>>>(partials, D, out);
}

// Round 11
// 163.957 us; speedup vs baseline: 1.0815x; 1.0815x over previous
//
#include <hip/hip_runtime.h>

#define TPB 256

// Gaussian kernel, sigma=1.1, ksize=5 (precomputed, normalized)
#define K0 0.0707663f
#define K1 0.2444606f
#define K2 0.3695462f

// energy/gradmag f4-unit block counts per scale (B=2): units = 2*N*N*(N/4)
#define EB0 8000
#define EB1 1000
#define EB2 125
// blur y4-units per scale
#define BB0 2000
#define BB1 250
#define BB2 32      // guard idx<8000
// resize: f4 units M=80: ds1 768000 + is1 256000 ; scalar M=40: ds2 384000 + is2 128000
// total thread-units = 1,536,000 -> 6000 blocks exact
#define RBLK 6000

typedef float f4 __attribute__((ext_vector_type(4)));

__device__ __forceinline__ f4 ld4(const float* __restrict__ p) { return *(const f4*)p; }

// reflect index (no edge repeat): j<0 -> -j, j>=n -> 2n-2-j
__device__ __forceinline__ int rref(int i, int n) {
    return i < 0 ? -i : (i >= n ? 2 * n - 2 - i : i);
}

// -------- resize 160->80, f4 over z. ratio = 159/79 = 2 + 1/79 -> i0 = 2i exactly --------
__device__ __forceinline__ void resize80_f4(const float* __restrict__ in,
                                            float* __restrict__ out, long idx) {
    int z4 = (int)(idx % 20); long r = idx / 20;
    int y = (int)(r % 80); r /= 80;
    int x = (int)(r % 80); int bc = (int)(r / 80);
    int z = z4 * 4;

    const float RT = 159.f / 79.f;
    float wx = (float)x * RT - (float)(2 * x);
    float wy = (float)y * RT - (float)(2 * y);
    const float* p = in + (long)bc * 4096000L + (long)(2 * x) * 25600 + (long)(2 * y) * 160 + 2 * z;
    f4 a00 = ld4(p),         a01 = ld4(p + 4);       // (x0,y0) z-window
    f4 b00 = ld4(p + 160),   b01 = ld4(p + 164);     // (x0,y1)
    f4 c00 = ld4(p + 25600), c01 = ld4(p + 25604);   // (x1,y0)
    f4 d00 = ld4(p + 25760), d01 = ld4(p + 25764);   // (x1,y1)

    f4 outv;
#pragma unroll
    for (int j = 0; j < 4; ++j) {
        int zo = z + j;
        float wz = (float)zo * RT - (float)(2 * zo);
        float e0, e1, f0, f1, g0, g1, h0, h1;
        if (j < 2) {
            e0 = a00[2 * j]; e1 = a00[2 * j + 1]; f0 = b00[2 * j]; f1 = b00[2 * j + 1];
            g0 = c00[2 * j]; g1 = c00[2 * j + 1]; h0 = d00[2 * j]; h1 = d00[2 * j + 1];
        } else {
            e0 = a01[2 * j - 4]; e1 = a01[2 * j - 3]; f0 = b01[2 * j - 4]; f1 = b01[2 * j - 3];
            g0 = c01[2 * j - 4]; g1 = c01[2 * j - 3]; h0 = d01[2 * j - 4]; h1 = d01[2 * j - 3];
        }
        float za = e0 + wz * (e1 - e0);
        float zb = f0 + wz * (f1 - f0);
        float zc = g0 + wz * (g1 - g0);
        float zd = h0 + wz * (h1 - h0);
        float cy0 = za + wy * (zb - za);
        float cy1 = zc + wy * (zd - zc);
        outv[j] = cy0 + wx * (cy1 - cy0);
    }
    *(f4*)(out + (long)bc * 512000L + (long)x * 6400 + (long)y * 80 + z) = outv;
}

// -------- scalar trilinear resize (for M=40), align_corners --------
template <int NIN, int M>
__device__ __forceinline__ void resize_one(const float* __restrict__ in,
                                           float* __restrict__ out, long idx) {
    constexpr float ratio = (float)((NIN - 1.0) / (M - 1.0));
    int z = (int)(idx % M); long r = idx / M;
    int y = (int)(r % M);   r /= M;
    int x = (int)(r % M);   int bc = (int)(r / M);

    float cx = (float)x * ratio, cy = (float)y * ratio, cz = (float)z * ratio;
    int x0 = min((int)cx, NIN - 1), y0 = min((int)cy, NIN - 1), z0 = min((int)cz, NIN - 1);
    float wx = cx - (float)x0, wy = cy - (float)y0, wz = cz - (float)z0;
    int x1 = min(x0 + 1, NIN - 1), y1 = min(y0 + 1, NIN - 1), z1 = min(z0 + 1, NIN - 1);

    const float* p = in + (long)bc * NIN * NIN * NIN;
    constexpr long sx = (long)NIN * NIN;
#define AT(xi, yi, zi) p[(long)(xi) * sx + (long)(yi) * NIN + (zi)]
    float c00 = AT(x0, y0, z0) * (1.f - wz) + AT(x0, y0, z1) * wz;
    float c01 = AT(x0, y1, z0) * (1.f - wz) + AT(x0, y1, z1) * wz;
    float c10 = AT(x1, y0, z0) * (1.f - wz) + AT(x1, y0, z1) * wz;
    float c11 = AT(x1, y1, z0) * (1.f - wz) + AT(x1, y1, z1) * wz;
#undef AT
    float c0 = c00 * (1.f - wy) + c01 * wy;
    float c1 = c10 * (1.f - wy) + c11 * wy;
    out[idx] = c0 * (1.f - wx) + c1 * wx;
}

__global__ __launch_bounds__(TPB)
void resize_all_kernel(const float* __restrict__ D, const float* __restrict__ I,
                       float* __restrict__ ds1, float* __restrict__ ds2,
                       float* __restrict__ is1, float* __restrict__ is2) {
    long idx = (long)blockIdx.x * TPB + threadIdx.x;
    // block-aligned ranges: 3000 | 1000 | 1500 | 500 blocks
    if (idx < 768000L) { resize80_f4(D, ds1, idx); return; }
    idx -= 768000L;
    if (idx < 256000L) { resize80_f4(I, is1, idx); return; }
    idx -= 256000L;
    if (idx < 384000L) { resize_one<160, 40>(D, ds2, idx); return; }
    idx -= 384000L;
    resize_one<160, 40>(I, is2, idx);
}

// -------- gradient magnitude, f4 over z (per-f4, round-7 form) --------
template <int N>
__device__ __forceinline__ void gradmag_one(const float* __restrict__ img,
                                            float* __restrict__ g, long idx) {
    constexpr int NZ4 = N / 4;
    constexpr long n2 = (long)N * N, n3 = n2 * N;
    int z4 = (int)(idx % NZ4); long r = idx / NZ4;
    int y = (int)(r % N); r /= N;
    int x = (int)(r % N); int b = (int)(r / N);
    int z = z4 * 4;

    const float* base = img + (long)b * n3;
    const float* rowc = base + (long)x * n2 + (long)y * N;
    f4 cur = ld4(rowc + z);
    f4 prev = (z > 0) ? ld4(rowc + z - 4) : cur;
    f4 next = (z + 4 < N) ? ld4(rowc + z + 4) : cur;

    int xm = max(x - 1, 0), xp = min(x + 1, N - 1);
    int ym = max(y - 1, 0), yp = min(y + 1, N - 1);
    float hx = (x == 0 || x == N - 1) ? 1.f : 0.5f;
    float hy = (y == 0 || y == N - 1) ? 1.f : 0.5f;
    f4 rxp = ld4(base + (long)xp * n2 + (long)y * N + z);
    f4 rxm = ld4(base + (long)xm * n2 + (long)y * N + z);
    f4 ryp = ld4(base + (long)x * n2 + (long)yp * N + z);
    f4 rym = ld4(base + (long)x * n2 + (long)ym * N + z);

    f4 outv;
#pragma unroll
    for (int j = 0; j < 4; ++j) {
        float c = cur[j];
        float zmv = (j == 0) ? prev[3] : cur[(j == 0) ? 0 : j - 1];
        float zpv = (j == 3) ? next[0] : cur[(j == 3) ? 3 : j + 1];
        int gz = z + j;
        float dz = (gz == 0) ? (zpv - c) : ((gz == N - 1) ? (c - zmv) : 0.5f * (zpv - zmv));
        float dx = hx * (rxp[j] - rxm[j]);
        float dy = hy * (ryp[j] - rym[j]);
        outv[j] = sqrtf(dx * dx + dy * dy + dz * dz);
    }
    *(f4*)(g + (long)b * n3 + (long)x * n2 + (long)y * N + z) = outv;
}

__global__ __launch_bounds__(TPB)
void gradmag_all(const float* __restrict__ I0, const float* __restrict__ is1,
                 const float* __restrict__ is2, float* __restrict__ g0,
                 float* __restrict__ g1, float* __restrict__ g2) {
    int blk = blockIdx.x;
    if (blk < EB0)            gradmag_one<160>(I0,  g0, (long)blk * TPB + threadIdx.x);
    else if (blk < EB0 + EB1) gradmag_one<80> (is1, g1, (long)(blk - EB0) * TPB + threadIdx.x);
    else                      gradmag_one<40> (is2, g2, (long)(blk - EB0 - EB1) * TPB + threadIdx.x);
}

// -------- fused blur x+y, 4 outputs per thread along y (column-sum reuse) --------
template <int N>
__device__ __forceinline__ void blur_one(const float* __restrict__ in,
                                         float* __restrict__ out, long idx) {
    constexpr int NZ4 = N / 4, NY4 = N / 4;
    constexpr long n2 = (long)N * N, n3 = n2 * N;
    int z4 = (int)(idx % NZ4); long r = idx / NZ4;
    int y4 = (int)(r % NY4); r /= NY4;
    int x = (int)(r % N); int b = (int)(r / N);
    int y0 = y4 * 4, z = z4 * 4;

    const float K[5] = {K0, K1, K2, K1, K0};
    const float* base = in + (long)b * n3 + z;

    f4 cs[8];
#pragma unroll
    for (int jj = 0; jj < 8; ++jj) cs[jj] = (f4){0.f, 0.f, 0.f, 0.f};

#pragma unroll
    for (int i = 0; i < 5; ++i) {
        int qx = rref(x + i - 2, N);
        const float* px = base + (long)qx * n2;
#pragma unroll
        for (int jj = 0; jj < 8; ++jj) {
            int qy = rref(y0 - 2 + jj, N);
            cs[jj] += K[i] * ld4(px + (long)qy * N);
        }
    }
    float* ob = out + (long)b * n3 + (long)x * n2 + z;
#pragma unroll
    for (int k = 0; k < 4; ++k) {
        f4 o = K0 * cs[k] + K1 * cs[k + 1] + K2 * cs[k + 2] + K1 * cs[k + 3] + K0 * cs[k + 4];
        *(f4*)(ob + (long)(y0 + k) * N) = o;
    }
}

__global__ __launch_bounds__(TPB)
void blur_all(const float* __restrict__ g0, const float* __restrict__ g1,
              const float* __restrict__ g2, float* __restrict__ t0,
              float* __restrict__ t1, float* __restrict__ t2) {
    int blk = blockIdx.x;
    if (blk < BB0)            blur_one<160>(g0, t0, (long)blk * TPB + threadIdx.x);
    else if (blk < BB0 + BB1) blur_one<80> (g1, t1, (long)(blk - BB0) * TPB + threadIdx.x);
    else {
        long idx = (long)(blk - BB0 - BB1) * TPB + threadIdx.x;
        if (idx < 8000) blur_one<40>(g2, t2, idx);
    }
}

// -------- Lame strain energy + in-register blur-z of igxy (per-f4, frozen form) ----
template <int N>
__device__ __forceinline__ float energy_one(const float* __restrict__ def,
                                            const float* __restrict__ igxy, long idx) {
    constexpr int NZ4 = N / 4;
    constexpr long n2 = (long)N * N, n3 = n2 * N;
    int z4 = (int)(idx % NZ4); long r = idx / NZ4;
    int y = (int)(r % N); r /= N;
    int x = (int)(r % N); int b = (int)(r / N);
    int z = z4 * 4;

    int xm = max(x - 1, 0), xp = min(x + 1, N - 1);
    int ym = max(y - 1, 0), yp = min(y + 1, N - 1);
    float hx = (x == 0 || x == N - 1) ? 1.f : 0.5f;
    float hy = (y == 0 || y == N - 1) ? 1.f : 0.5f;

    const float* base = def + (long)b * 3 * n3;
    long sp = (long)x * n2 + (long)y * N + z;

    f4 CC[3], CP[3], CN[3], RXP[3], RXM[3], RYP[3], RYM[3];
#pragma unroll
    for (int c = 0; c < 3; ++c) {
        const float* rc = base + (long)c * n3 + sp;
        CC[c] = ld4(rc);
        CP[c] = (z > 0) ? ld4(rc - 4) : CC[c];
        CN[c] = (z + 4 < N) ? ld4(rc + 4) : CC[c];
        RXP[c] = ld4(base + (long)c * n3 + (long)xp * n2 + (long)y * N + z);
        RXM[c] = ld4(base + (long)c * n3 + (long)xm * n2 + (long)y * N + z);
        RYP[c] = ld4(base + (long)c * n3 + (long)x * n2 + (long)yp * N + z);
        RYM[c] = ld4(base + (long)c * n3 + (long)x * n2 + (long)ym * N + z);
    }

    const float* growc = igxy + (long)b * n3 + (long)x * n2 + (long)y * N;
    f4 gcur = ld4(growc + z);
    f4 gprev, gnext;
    if (z >= 4) gprev = ld4(growc + z - 4);
    else { gprev[0] = growc[4]; gprev[1] = growc[3]; gprev[2] = growc[2]; gprev[3] = growc[1]; }
    if (z + 8 <= N) gnext = ld4(growc + z + 4);
    else { gnext[0] = growc[N - 2]; gnext[1] = growc[N - 3]; gnext[2] = growc[N - 4]; gnext[3] = growc[N - 5]; }
    float gw[12];
#pragma unroll
    for (int i = 0; i < 4; ++i) { gw[i] = gprev[i]; gw[4 + i] = gcur[i]; gw[8 + i] = gnext[i]; }

    float lsum = 0.f;
#pragma unroll
    for (int j = 0; j < 4; ++j) {
        int gz = z + j;
        float dX[3], dY[3], dZ[3];
#pragma unroll
        for (int c = 0; c < 3; ++c) {
            float cc = CC[c][j];
            float zmv = (j == 0) ? CP[c][3] : CC[c][(j == 0) ? 0 : j - 1];
            float zpv = (j == 3) ? CN[c][0] : CC[c][(j == 3) ? 3 : j + 1];
            dZ[c] = (gz == 0) ? (zpv - cc)
                              : ((gz == N - 1) ? (cc - zmv) : 0.5f * (zpv - zmv));
            dX[c] = hx * (RXP[c][j] - RXM[c][j]);
            dY[c] = hy * (RYP[c][j] - RYM[c][j]);
        }
        float igv = K0 * gw[2 + j] + K1 * gw[3 + j] + K2 * gw[4 + j]
                  + K1 * gw[5 + j] + K0 * gw[6 + j];
        float lam = fminf(fmaxf(1.0f + 2.0f * igv, 0.1f), 10.0f);
        float mu  = fminf(fmaxf(0.5f + 1.0f * igv, 0.1f), 10.0f);
        float wt  = 1.0f + 5.0f * igv;

        float Exx = dX[0], Eyy = dY[1], Ezz = dZ[2];
        float Exy = 0.5f * (dY[0] + dX[1]);
        float Exz = 0.5f * (dZ[0] + dX[2]);
        float Eyz = 0.5f * (dZ[1] + dY[2]);
        float tr = Exx + Eyy + Ezz;
        float e = 0.5f * lam * tr * tr +
                  mu * (Exx * Exx + Eyy * Eyy + Ezz * Ezz +
                        2.0f * (Exy * Exy + Exz * Exz + Eyz * Eyz));
        lsum += wt * e;
    }
    return lsum;
}

__global__ __launch_bounds__(TPB)
void energy_all(const float* __restrict__ D, const float* __restrict__ ds1,
                const float* __restrict__ ds2, const float* __restrict__ t0,
                const float* __restrict__ t1, const float* __restrict__ t2,
                float* __restrict__ partial) {
    int blk = blockIdx.x;
    float lsum;
    if (blk < EB0)            lsum = energy_one<160>(D,   t0, (long)blk * TPB + threadIdx.x);
    else if (blk < EB0 + EB1) lsum = energy_one<80> (ds1, t1, (long)(blk - EB0) * TPB + threadIdx.x);
    else                      lsum = energy_one<40> (ds2, t2, (long)(blk - EB0 - EB1) * TPB + threadIdx.x);

    __shared__ float sm[TPB];
    sm[threadIdx.x] = lsum;
    __syncthreads();
    for (int s = TPB / 2; s > 0; s >>= 1) {
        if (threadIdx.x < s) sm[threadIdx.x] += sm[threadIdx.x + s];
        __syncthreads();
    }
    if (threadIdx.x == 0) partial[blk] = sm[0];
}

// -------- combine scale partials + Jacobian penalty -> out[0] --------
__global__ __launch_bounds__(TPB)
void finalize_kernel(const float* __restrict__ partial,
                     const float* __restrict__ def, float* __restrict__ out) {
    __shared__ float sm[TPB];
    const float wts[3] = {1.0f, 0.5f, 0.25f};
    const float invcnt[3] = {1.0f / (2.0f * 160 * 160 * 160),
                             1.0f / (2.0f * 80 * 80 * 80),
                             1.0f / (2.0f * 40 * 40 * 40)};
    const int offs[3] = {0, EB0, EB0 + EB1};
    const int cnts[3] = {EB0, EB1, EB2};
    float acc = 0.f;
    for (int s = 0; s < 3; ++s) {
        float local = 0.f;
        for (int i = threadIdx.x; i < cnts[s]; i += TPB) local += partial[offs[s] + i];
        acc += wts[s] * invcnt[s] * local;
    }
    sm[threadIdx.x] = acc;
    __syncthreads();
    for (int s = TPB / 2; s > 0; s >>= 1) {
        if (threadIdx.x < s) sm[threadIdx.x] += sm[threadIdx.x + s];
        __syncthreads();
    }
    if (threadIdx.x == 0) {
        float jac = 0.f;
        const int n = 160;
        long n3 = (long)n * n * n;
        long ctr = ((long)80 * n + 80) * n + 80;
        for (int b = 0; b < 2; ++b) {
            const float* p = def + (long)b * 3 * n3;
            float J[3][3];
            for (int c = 0; c < 3; ++c) {
                const float* q = p + (long)c * n3 + ctr;
                J[c][0] = 0.5f * (q[(long)n * n] - q[-(long)n * n]);
                J[c][1] = 0.5f * (q[n] - q[-n]);
                J[c][2] = 0.5f * (q[1] - q[-1]);
            }
            float det = J[0][0] * (J[1][1] * J[2][2] - J[1][2] * J[2][1])
                      - J[0][1] * (J[1][0] * J[2][2] - J[1][2] * J[2][0])
                      + J[0][2] * (J[1][0] * J[2][1] - J[1][1] * J[2][0]);
            jac += fmaxf(-det, 0.f);
        }
        jac *= 0.5f; // mean over B=2
        out[0] = sm[0] + 0.1f * jac;
    }
}

extern "C" void kernel_launch(void* const* d_in, const int* in_sizes, int n_in,
                              void* d_out, int out_size, void* d_ws, size_t ws_size,
                              hipStream_t stream) {
    const float* D = (const float*)d_in[0];  // (2,3,160,160,160)
    const float* I = (const float*)d_in[1];  // (2,1,160,160,160)
    float* out = (float*)d_out;
    float* ws = (float*)d_ws;

    const int B = 2;
    const long S0 = (long)B * 160 * 160 * 160;
    const long S1 = (long)B * 80 * 80 * 80;
    const long S2 = (long)B * 40 * 40 * 40;

    // disjoint workspace layout
    float* partials = ws;                 // 9216 (uses [0, 9125))
    float* ds1 = partials + 9216;         // 3*S1
    float* is1 = ds1 + 3 * S1;            // S1
    float* g1  = is1 + S1;                // S1
    float* t1  = g1 + S1;                 // S1
    float* ds2 = t1 + S1;                 // 3*S2
    float* is2 = ds2 + 3 * S2;            // S2
    float* g2  = is2 + S2;                // S2
    float* t2  = g2 + S2;                 // S2
    float* g0  = t2 + S2;                 // S0
    float* t0  = g0 + S0;                 // S0

    // 1) all four resizes (M=80 f4-vectorized, M=40 scalar)
    resize_all_kernel<<<RBLK, TPB, 0, stream>>>(D, I, ds1, ds2, is1, is2);
    // 2) gradmag, all scales (per-f4)
    gradmag_all<<<EB0 + EB1 + EB2, TPB, 0, stream>>>(I, is1, is2, g0, g1, g2);
    // 3) blur x+y, all scales (y4)
    blur_all<<<BB0 + BB1 + BB2, TPB, 0, stream>>>(g0, g1, g2, t0, t1, t2);
    // 4) energy (+ in-register z-blur), all scales (per-f4, frozen)
    energy_all<<<EB0 + EB1 + EB2, TPB, 0, stream>>>(D, ds1, ds2, t0, t1, t2, partials);
    // 5) finalize
    finalize_kernel<<<1, TPB, 0, stream>>>(partials, D, out);
}